// Round 1
// baseline (480.225 us; speedup 1.0000x reference)
//
#include <hip/hip_runtime.h>
#include <cstdint>
#include <cstddef>

#define BATCH 8
#define NODES 2048
#define IN_DIM 64
#define DTOT 128
#define NKEY 1024
#define TILE_N 16

__device__ __forceinline__ unsigned long long shfl_xor_u64(unsigned long long x, int mask) {
    int lo = (int)(unsigned)(x & 0xffffffffull);
    int hi = (int)(unsigned)(x >> 32);
    lo = __shfl_xor(lo, mask, 64);
    hi = __shfl_xor(hi, mask, 64);
    return ((unsigned long long)(unsigned)hi << 32) | (unsigned)lo;
}

__device__ __forceinline__ unsigned long long make_key(float v, int idx) {
    unsigned u = __float_as_uint(v);
    u = (u & 0x80000000u) ? ~u : (u | 0x80000000u);
    return ((unsigned long long)u << 32) | (unsigned)(1023 - idx);
}

// ---------------- Kernel A: q/k projection ----------------
// q_ws[b][n][c] = sum_d x[b][n][d]*Wq[c][d] + bq[c]   (all n)
// k_ws[b][u][c] = same with Wk,bk                     (u < 1024 only)
__global__ __launch_bounds__(256) void proj_qk(
    const float* __restrict__ x, const float* __restrict__ Wq, const float* __restrict__ bq,
    const float* __restrict__ Wk, const float* __restrict__ bk,
    float* __restrict__ qws, float* __restrict__ kws)
{
    __shared__ float xld[16 * 68];   // 16 rows x 64, pad 68
    const int t = threadIdx.x;
    const int blk = blockIdx.x;
    const int b = blk >> 7;            // 128 tiles per batch
    const int n0 = (blk & 127) << 4;   // *16

    {   // load x tile: 256 float4 = 16x64 floats
        const int r = t >> 4, d4 = t & 15;
        float4 v = *(const float4*)(x + ((size_t)(b * NODES + n0 + r)) * IN_DIM + d4 * 4);
        *(float4*)(xld + r * 68 + d4 * 4) = v;
    }
    __syncthreads();

    const int c = t & 127;
    const int grp = t >> 7;   // 0..1, 8 rows each
    float acc[8];
    #pragma unroll
    for (int i = 0; i < 8; ++i) acc[i] = bq[c];
    #pragma unroll
    for (int d4 = 0; d4 < 16; ++d4) {
        float4 w4 = *(const float4*)(Wq + c * IN_DIM + d4 * 4);
        #pragma unroll
        for (int i = 0; i < 8; ++i) {
            float4 x4 = *(const float4*)(xld + (grp * 8 + i) * 68 + d4 * 4);
            acc[i] += w4.x * x4.x + w4.y * x4.y + w4.z * x4.z + w4.w * x4.w;
        }
    }
    #pragma unroll
    for (int i = 0; i < 8; ++i)
        qws[((size_t)(b * NODES + n0 + grp * 8 + i)) * DTOT + c] = acc[i];

    if (n0 < NKEY) {
        #pragma unroll
        for (int i = 0; i < 8; ++i) acc[i] = bk[c];
        #pragma unroll
        for (int d4 = 0; d4 < 16; ++d4) {
            float4 w4 = *(const float4*)(Wk + c * IN_DIM + d4 * 4);
            #pragma unroll
            for (int i = 0; i < 8; ++i) {
                float4 x4 = *(const float4*)(xld + (grp * 8 + i) * 68 + d4 * 4);
                acc[i] += w4.x * x4.x + w4.y * x4.y + w4.z * x4.z + w4.w * x4.w;
            }
        }
        #pragma unroll
        for (int i = 0; i < 8; ++i)
            kws[((size_t)(b * NKEY + n0 + grp * 8 + i)) * DTOT + c] = acc[i];
    }
}

// ---------------- Kernel B: scores + top-32 + adjacency write ----------------
__global__ __launch_bounds__(256) void scores_topk(
    const float* __restrict__ qws, const float* __restrict__ kws,
    const float* __restrict__ mlpw, const float* __restrict__ mlpb,
    float* __restrict__ adj)
{
    __shared__ float sc[16 * 1024];            // 64 KB scores
    __shared__ float qld[16 * 132];            // q tile, pad 132
    __shared__ float kld[256 * 36];            // k chunk: 256 u x 32 d, pad 36
    __shared__ unsigned long long cand[4][64]; // per-wave candidate buffer

    const int t = threadIdx.x;
    const int blk = blockIdx.x;
    const int b = blk >> 7;
    const int n0 = (blk & 127) << 4;
    const int w = t >> 6, l = t & 63;
    const int u_sel = l & 15, n_sel = l >> 4;

    // load q tile: 512 float4 (16 rows x 32 f4)
    #pragma unroll
    for (int rep = 0; rep < 2; ++rep) {
        int f = rep * 256 + t;
        int r = f >> 5, d4 = f & 31;
        float4 v = *(const float4*)(qws + ((size_t)(b * NODES + n0 + r)) * DTOT + d4 * 4);
        *(float4*)(qld + r * 132 + d4 * 4) = v;
    }

    float mw[4][4], mb4[4];
    #pragma unroll
    for (int o = 0; o < 4; ++o) {
        mb4[o] = mlpb[o];
        #pragma unroll
        for (int h = 0; h < 4; ++h) mw[o][h] = mlpw[o * 4 + h];
    }
    const float INV = 0.17677669529663687f;  // 1/sqrt(32)

    for (int ut = 0; ut < 4; ++ut) {
        float acc[4][4][4];  // [head=dc][i][j]
        #pragma unroll
        for (int h = 0; h < 4; ++h)
            #pragma unroll
            for (int i = 0; i < 4; ++i)
                #pragma unroll
                for (int j = 0; j < 4; ++j) acc[h][i][j] = 0.f;

        #pragma unroll
        for (int dc = 0; dc < 4; ++dc) {
            __syncthreads();
            // stage k chunk: 2048 float4 (256 rows x 8 f4)
            #pragma unroll
            for (int jj = 0; jj < 8; ++jj) {
                int f = jj * 256 + t;
                int ur = f >> 3, d4 = f & 7;
                float4 v = *(const float4*)(kws + ((size_t)(b * NKEY + ut * 256 + ur)) * DTOT + dc * 32 + d4 * 4);
                *(float4*)(kld + ur * 36 + d4 * 4) = v;
            }
            __syncthreads();
            #pragma unroll
            for (int d4 = 0; d4 < 8; ++d4) {
                float4 qv[4], kv[4];
                #pragma unroll
                for (int i = 0; i < 4; ++i)
                    qv[i] = *(const float4*)(qld + (n_sel * 4 + i) * 132 + dc * 32 + d4 * 4);
                #pragma unroll
                for (int j = 0; j < 4; ++j)
                    kv[j] = *(const float4*)(kld + (w * 64 + j * 16 + u_sel) * 36 + d4 * 4);
                #pragma unroll
                for (int i = 0; i < 4; ++i)
                    #pragma unroll
                    for (int j = 0; j < 4; ++j)
                        acc[dc][i][j] += qv[i].x * kv[j].x + qv[i].y * kv[j].y +
                                         qv[i].z * kv[j].z + qv[i].w * kv[j].w;
            }
        }
        // epilogue -> scores
        #pragma unroll
        for (int i = 0; i < 4; ++i)
            #pragma unroll
            for (int j = 0; j < 4; ++j) {
                float a0 = acc[0][i][j] * INV, a1 = acc[1][i][j] * INV;
                float a2 = acc[2][i][j] * INV, a3 = acc[3][i][j] * INV;
                float ssum = a0 + a1 + a2 + a3;
                #pragma unroll
                for (int o = 0; o < 4; ++o) {
                    float to = mw[o][0] * a0 + mw[o][1] * a1 + mw[o][2] * a2 + mw[o][3] * a3 + mb4[o];
                    ssum += fmaxf(to, 0.f);
                }
                sc[(n_sel * 4 + i) * 1024 + ut * 256 + w * 64 + j * 16 + u_sel] = ssum;
            }
    }
    __syncthreads();

    // ---- top-32 per row; wave w handles rows w, w+4, w+8, w+12 ----
    for (int rr = 0; rr < 4; ++rr) {
        const int r = w + rr * 4;
        const int base = r * 1024;
        float v[16];
        #pragma unroll
        for (int jj = 0; jj < 16; ++jj) v[jj] = sc[base + l + (jj << 6)];

        float lm = v[0];
        #pragma unroll
        for (int jj = 1; jj < 16; ++jj) lm = fmaxf(lm, v[jj]);

        // descending bitonic sort of the 64 lane maxima -> T0 = 32nd largest
        float s = lm;
        #pragma unroll
        for (int k = 2; k <= 64; k <<= 1) {
            #pragma unroll
            for (int j = k >> 1; j > 0; j >>= 1) {
                float o = __shfl_xor(s, j, 64);
                bool up = ((l & k) == 0);
                bool lower = ((l & j) == 0);
                float mx = fmaxf(s, o), mn = fminf(s, o);
                s = (up == lower) ? mx : mn;
            }
        }
        const float T0 = __shfl(s, 31, 64);  // guarantees >=32 elements >= T0

        // ballot-compact candidates >= T0
        cand[w][l] = 0ull;
        __builtin_amdgcn_wave_barrier();
        int total = 0;
        #pragma unroll
        for (int jj = 0; jj < 16; ++jj) {
            bool p = (v[jj] >= T0);
            unsigned long long m = __ballot(p);
            if (p) {
                int pos = total + __popcll(m & ((1ull << l) - 1ull));
                if (pos < 64) cand[w][pos] = make_key(v[jj], l + (jj << 6));
            }
            total += (int)__popcll(m);
        }
        __builtin_amdgcn_wave_barrier();

        unsigned long long key;
        if (total <= 64) {
            key = cand[w][l];
            // descending bitonic sort of 64 u64 keys
            #pragma unroll
            for (int k = 2; k <= 64; k <<= 1) {
                #pragma unroll
                for (int j = k >> 1; j > 0; j >>= 1) {
                    unsigned long long o = shfl_xor_u64(key, j);
                    bool up = ((l & k) == 0);
                    bool lower = ((l & j) == 0);
                    unsigned long long mx = key > o ? key : o;
                    unsigned long long mn = key > o ? o : key;
                    key = (up == lower) ? mx : mn;
                }
            }
        } else {
            // rare fallback: 32 rounds of exact butterfly extraction
            float selv = 0.f; int seli = 0;
            #pragma unroll 1
            for (int it = 0; it < 32; ++it) {
                float bv = -3.4e38f; int bi = 0x7fffffff;
                #pragma unroll
                for (int jj = 0; jj < 16; ++jj) {
                    int idx = l + (jj << 6);
                    if (v[jj] > bv) { bv = v[jj]; bi = idx; }
                }
                #pragma unroll
                for (int off = 1; off < 64; off <<= 1) {
                    float ov = __shfl_xor(bv, off, 64);
                    int oi = __shfl_xor(bi, off, 64);
                    if (ov > bv || (ov == bv && oi < bi)) { bv = ov; bi = oi; }
                }
                if (l == it) { selv = bv; seli = bi; }
                if ((bi & 63) == l) {
                    int slot = bi >> 6;
                    #pragma unroll
                    for (int jj = 0; jj < 16; ++jj) if (jj == slot) v[jj] = -3.4e38f;
                }
            }
            key = (l < 32) ? make_key(selv, seli) : 0ull;
        }

        // rebuild the row: zeros + 32 selected (DS pipe is in-order per wave)
        __builtin_amdgcn_wave_barrier();
        #pragma unroll
        for (int jj = 0; jj < 16; ++jj) sc[base + l + (jj << 6)] = 0.f;
        __builtin_amdgcn_wave_barrier();
        if (l < 32) {
            unsigned hi = (unsigned)(key >> 32);
            float val = __uint_as_float((hi & 0x80000000u) ? (hi & 0x7fffffffu) : ~hi);
            int idx = 1023 - (int)(key & 0xffffffffu);
            sc[base + idx] = val;
        }
        __builtin_amdgcn_wave_barrier();
    }
    __syncthreads();

    // ---- coalesced write of 16 adjacency rows (2048 wide, cols >=1024 are zero) ----
    const size_t obase = ((size_t)b * NODES + n0) * NODES;
    #pragma unroll
    for (int jj = 0; jj < 32; ++jj) {
        int f = jj * 256 + t;
        int r = f >> 9, c4 = f & 511;
        float4 val;
        if (c4 < 256) val = *(const float4*)(sc + r * 1024 + c4 * 4);
        else          val = make_float4(0.f, 0.f, 0.f, 0.f);
        *(float4*)(adj + obase + (size_t)r * NODES + c4 * 4) = val;
    }
}

extern "C" void kernel_launch(void* const* d_in, const int* in_sizes, int n_in,
                              void* d_out, int out_size, void* d_ws, size_t ws_size,
                              hipStream_t stream) {
    const float* x    = (const float*)d_in[0];
    const float* Wq   = (const float*)d_in[1];
    const float* bq   = (const float*)d_in[2];
    const float* Wk   = (const float*)d_in[3];
    const float* bk   = (const float*)d_in[4];
    const float* mlpw = (const float*)d_in[5];
    const float* mlpb = (const float*)d_in[6];
    // d_in[7], d_in[8] (ln_g, ln_b) feed only the deleted adj_static -> unused.

    float* qws = (float*)d_ws;                           // 8*2048*128 f32 = 8 MB
    float* kws = qws + (size_t)BATCH * NODES * DTOT;     // 8*1024*128 f32 = 4 MB
    float* adj = (float*)d_out;

    proj_qk<<<dim3(BATCH * (NODES / TILE_N)), dim3(256), 0, stream>>>(x, Wq, bq, Wk, bk, qws, kws);
    scores_topk<<<dim3(BATCH * (NODES / TILE_N)), dim3(256), 0, stream>>>(qws, kws, mlpw, mlpb, adj);
}

// Round 2
// 239.452 us; speedup vs baseline: 2.0055x; 2.0055x over previous
//
#include <hip/hip_runtime.h>
#include <cstdint>
#include <cstddef>

#define BATCH 8
#define NODES 2048
#define IN_DIM 64
#define DTOT 128
#define NKEY 1024

__device__ __forceinline__ unsigned long long shfl_xor_u64(unsigned long long x, int mask) {
    int lo = (int)(unsigned)(x & 0xffffffffull);
    int hi = (int)(unsigned)(x >> 32);
    lo = __shfl_xor(lo, mask, 64);
    hi = __shfl_xor(hi, mask, 64);
    return ((unsigned long long)(unsigned)hi << 32) | (unsigned)lo;
}

__device__ __forceinline__ unsigned long long make_key(float v, int idx) {
    unsigned u = __float_as_uint(v);
    u = (u & 0x80000000u) ? ~u : (u | 0x80000000u);
    return ((unsigned long long)u << 32) | (unsigned)(1023 - idx);
}

// ---------------- Kernel 1: q/k projection, 64x64 GEMM tiles ----------------
// Block covers 64 rows x 64 output cols. Grid enumerates:
//   per batch: 32 n-tiles x 2 c-tiles for q (2048 rows x 128 cols)
//            + 16 n-tiles x 2 c-tiles for k (1024 rows x 128 cols)  = 96 blocks
__global__ __launch_bounds__(256) void proj_qk(
    const float* __restrict__ x, const float* __restrict__ Wq, const float* __restrict__ bq,
    const float* __restrict__ Wk, const float* __restrict__ bk,
    float* __restrict__ qws, float* __restrict__ kws)
{
    __shared__ float xs[64 * 68];
    __shared__ float wsh[64 * 68];

    const int t = threadIdx.x;
    const int blk = blockIdx.x;
    const int b = blk / 96;
    const int idx = blk - b * 96;

    const float* W; const float* bias; float* out;
    int nbase, cbase; size_t orow;
    if (idx < 64) {           // q part
        int nt = idx >> 1, ct = idx & 1;
        nbase = nt * 64; cbase = ct * 64;
        W = Wq; bias = bq; out = qws;
        orow = (size_t)(b * NODES + nbase);
    } else {                  // k part
        int i2 = idx - 64;
        int nt = i2 >> 1, ct = i2 & 1;
        nbase = nt * 64; cbase = ct * 64;
        W = Wk; bias = bk; out = kws;
        orow = (size_t)(b * NKEY + nbase);
    }

    // stage x tile 64x64 and W tile 64x64 (1024 float4 each, 4/thread)
    #pragma unroll
    for (int rep = 0; rep < 4; ++rep) {
        int f = rep * 256 + t;
        int r = f >> 4, d4 = f & 15;
        float4 xv = *(const float4*)(x + ((size_t)(b * NODES + nbase + r)) * IN_DIM + d4 * 4);
        *(float4*)(xs + r * 68 + d4 * 4) = xv;
        float4 wv = *(const float4*)(W + (size_t)(cbase + r) * IN_DIM + d4 * 4);
        *(float4*)(wsh + r * 68 + d4 * 4) = wv;
    }
    __syncthreads();

    const int w = t >> 6, l = t & 63;
    const int n_sel = w * 4 + (l >> 4);   // 0..15 -> rows n_sel*4 + i
    const int ul = l & 15;                // cols j*16 + ul

    float acc[4][4];
    #pragma unroll
    for (int i = 0; i < 4; ++i)
        #pragma unroll
        for (int j = 0; j < 4; ++j) acc[i][j] = 0.f;

    #pragma unroll
    for (int d4 = 0; d4 < 16; ++d4) {
        float4 xv[4], wv[4];
        #pragma unroll
        for (int i = 0; i < 4; ++i)
            xv[i] = *(const float4*)(xs + (n_sel * 4 + i) * 68 + d4 * 4);
        #pragma unroll
        for (int j = 0; j < 4; ++j)
            wv[j] = *(const float4*)(wsh + (j * 16 + ul) * 68 + d4 * 4);
        #pragma unroll
        for (int i = 0; i < 4; ++i)
            #pragma unroll
            for (int j = 0; j < 4; ++j)
                acc[i][j] += xv[i].x * wv[j].x + xv[i].y * wv[j].y +
                             xv[i].z * wv[j].z + xv[i].w * wv[j].w;
    }

    #pragma unroll
    for (int j = 0; j < 4; ++j) {
        float bv = bias[cbase + j * 16 + ul];
        #pragma unroll
        for (int i = 0; i < 4; ++i)
            out[(orow + n_sel * 4 + i) * DTOT + cbase + j * 16 + ul] = acc[i][j] + bv;
    }
}

// ---------------- Kernel 2: scores (64n x 64u tiles) -> stash in d_out cols 1024.. ----------------
__global__ __launch_bounds__(256) void scores_gemm(
    const float* __restrict__ qws, const float* __restrict__ kws,
    const float* __restrict__ mlpw, const float* __restrict__ mlpb,
    float* __restrict__ adj)
{
    __shared__ float qs[64 * 36];
    __shared__ float ks[64 * 36];

    const int t = threadIdx.x;
    const int blk = blockIdx.x;
    const int b = blk >> 9;                 // 512 tiles/batch
    const int rem = blk & 511;
    const int nbase = (rem >> 4) * 64;      // 32 n-tiles
    const int ubase = (rem & 15) * 64;      // 16 u-tiles

    const int w = t >> 6, l = t & 63;
    const int n_sel = w * 4 + (l >> 4);
    const int ul = l & 15;

    float acc[4][4][4];   // [head][i][j]
    #pragma unroll
    for (int h = 0; h < 4; ++h)
        #pragma unroll
        for (int i = 0; i < 4; ++i)
            #pragma unroll
            for (int j = 0; j < 4; ++j) acc[h][i][j] = 0.f;

    #pragma unroll
    for (int dc = 0; dc < 4; ++dc) {
        __syncthreads();
        #pragma unroll
        for (int rep = 0; rep < 2; ++rep) {
            int f = rep * 256 + t;
            int r = f >> 3, d4 = f & 7;
            float4 qv = *(const float4*)(qws + ((size_t)(b * NODES + nbase + r)) * DTOT + dc * 32 + d4 * 4);
            *(float4*)(qs + r * 36 + d4 * 4) = qv;
            float4 kv = *(const float4*)(kws + ((size_t)(b * NKEY + ubase + r)) * DTOT + dc * 32 + d4 * 4);
            *(float4*)(ks + r * 36 + d4 * 4) = kv;
        }
        __syncthreads();
        #pragma unroll
        for (int d4 = 0; d4 < 8; ++d4) {
            float4 qv[4], kv[4];
            #pragma unroll
            for (int i = 0; i < 4; ++i)
                qv[i] = *(const float4*)(qs + (n_sel * 4 + i) * 36 + d4 * 4);
            #pragma unroll
            for (int j = 0; j < 4; ++j)
                kv[j] = *(const float4*)(ks + (j * 16 + ul) * 36 + d4 * 4);
            #pragma unroll
            for (int i = 0; i < 4; ++i)
                #pragma unroll
                for (int j = 0; j < 4; ++j)
                    acc[dc][i][j] += qv[i].x * kv[j].x + qv[i].y * kv[j].y +
                                     qv[i].z * kv[j].z + qv[i].w * kv[j].w;
        }
    }

    float mw[4][4], mb4[4];
    #pragma unroll
    for (int o = 0; o < 4; ++o) {
        mb4[o] = mlpb[o];
        #pragma unroll
        for (int h = 0; h < 4; ++h) mw[o][h] = mlpw[o * 4 + h];
    }
    const float INV = 0.17677669529663687f;  // 1/sqrt(32)

    #pragma unroll
    for (int i = 0; i < 4; ++i) {
        const size_t rowp = ((size_t)(b * NODES + nbase + n_sel * 4 + i)) * NODES + NKEY;
        #pragma unroll
        for (int j = 0; j < 4; ++j) {
            float a0 = acc[0][i][j] * INV, a1 = acc[1][i][j] * INV;
            float a2 = acc[2][i][j] * INV, a3 = acc[3][i][j] * INV;
            float ssum = a0 + a1 + a2 + a3;
            #pragma unroll
            for (int o = 0; o < 4; ++o) {
                float to = mw[o][0] * a0 + mw[o][1] * a1 + mw[o][2] * a2 + mw[o][3] * a3 + mb4[o];
                ssum += fmaxf(to, 0.f);
            }
            adj[rowp + ubase + j * 16 + ul] = ssum;   // stash score in always-zero column region
        }
    }
}

// ---------------- Kernel 3: per-row top-32 + final adjacency write ----------------
__global__ __launch_bounds__(256) void topk_write(float* __restrict__ adj)
{
    __shared__ float scrow[4][1024];
    __shared__ unsigned long long cand[4][64];

    const int t = threadIdx.x;
    const int blk = blockIdx.x;
    const int b = blk >> 9;
    const int r0 = (blk & 511) * 4;
    const int w = t >> 6, l = t & 63;

    const int n = r0 + w;
    float* rowptr = adj + ((size_t)(b * NODES + n)) * NODES;
    const float* S = rowptr + NKEY;

    float v[16];
    #pragma unroll
    for (int jj = 0; jj < 16; ++jj) v[jj] = S[l + (jj << 6)];

    float lm = v[0];
    #pragma unroll
    for (int jj = 1; jj < 16; ++jj) lm = fmaxf(lm, v[jj]);

    // descending bitonic sort of 64 lane maxima -> T0 = 32nd largest lane-max
    float s = lm;
    #pragma unroll
    for (int k = 2; k <= 64; k <<= 1) {
        #pragma unroll
        for (int j = k >> 1; j > 0; j >>= 1) {
            float o = __shfl_xor(s, j, 64);
            bool up = ((l & k) == 0);
            bool lower = ((l & j) == 0);
            float mx = fmaxf(s, o), mn = fminf(s, o);
            s = (up == lower) ? mx : mn;
        }
    }
    const float T0 = __shfl(s, 31, 64);  // >=32 elements are >= T0

    cand[w][l] = 0ull;
    __builtin_amdgcn_wave_barrier();
    int total = 0;
    #pragma unroll
    for (int jj = 0; jj < 16; ++jj) {
        bool p = (v[jj] >= T0);
        unsigned long long m = __ballot(p);
        if (p) {
            int pos = total + __popcll(m & ((1ull << l) - 1ull));
            if (pos < 64) cand[w][pos] = make_key(v[jj], l + (jj << 6));
        }
        total += (int)__popcll(m);
    }
    __builtin_amdgcn_wave_barrier();

    unsigned long long key;
    if (total <= 64) {
        key = cand[w][l];
        #pragma unroll
        for (int k = 2; k <= 64; k <<= 1) {
            #pragma unroll
            for (int j = k >> 1; j > 0; j >>= 1) {
                unsigned long long o = shfl_xor_u64(key, j);
                bool up = ((l & k) == 0);
                bool lower = ((l & j) == 0);
                unsigned long long mx = key > o ? key : o;
                unsigned long long mn = key > o ? o : key;
                key = (up == lower) ? mx : mn;
            }
        }
    } else {
        // rare fallback: 32 rounds of exact butterfly extraction
        float selv = 0.f; int seli = 0;
        #pragma unroll 1
        for (int it = 0; it < 32; ++it) {
            float bv = -3.4e38f; int bi = 0x7fffffff;
            #pragma unroll
            for (int jj = 0; jj < 16; ++jj) {
                int idx = l + (jj << 6);
                if (v[jj] > bv) { bv = v[jj]; bi = idx; }
            }
            #pragma unroll
            for (int off = 1; off < 64; off <<= 1) {
                float ov = __shfl_xor(bv, off, 64);
                int oi = __shfl_xor(bi, off, 64);
                if (ov > bv || (ov == bv && oi < bi)) { bv = ov; bi = oi; }
            }
            if (l == it) { selv = bv; seli = bi; }
            if ((bi & 63) == l) {
                int slot = bi >> 6;
                #pragma unroll
                for (int jj = 0; jj < 16; ++jj) if (jj == slot) v[jj] = -3.4e38f;
            }
        }
        key = (l < 32) ? make_key(selv, seli) : 0ull;
    }

    // rebuild lower half of the row in LDS (in-order DS pipe per wave)
    __builtin_amdgcn_wave_barrier();
    #pragma unroll
    for (int jj = 0; jj < 16; ++jj) scrow[w][l + (jj << 6)] = 0.f;
    __builtin_amdgcn_wave_barrier();
    if (l < 32) {
        unsigned hi = (unsigned)(key >> 32);
        float val = __uint_as_float((hi & 0x80000000u) ? (hi & 0x7fffffffu) : ~hi);
        int idx = 1023 - (int)(key & 0xffffffffu);
        scrow[w][idx] = val;
    }
    __builtin_amdgcn_wave_barrier();

    // stream out the full 2048-wide row (upper half zeros, overwriting the stash)
    #pragma unroll
    for (int jj = 0; jj < 8; ++jj) {
        int c4 = jj * 64 + l;
        float4 val;
        if (c4 < 256) val = *(const float4*)(&scrow[w][c4 * 4]);
        else          val = make_float4(0.f, 0.f, 0.f, 0.f);
        *(float4*)(rowptr + c4 * 4) = val;
    }
}

extern "C" void kernel_launch(void* const* d_in, const int* in_sizes, int n_in,
                              void* d_out, int out_size, void* d_ws, size_t ws_size,
                              hipStream_t stream) {
    const float* x    = (const float*)d_in[0];
    const float* Wq   = (const float*)d_in[1];
    const float* bq   = (const float*)d_in[2];
    const float* Wk   = (const float*)d_in[3];
    const float* bk   = (const float*)d_in[4];
    const float* mlpw = (const float*)d_in[5];
    const float* mlpb = (const float*)d_in[6];
    // ln_g, ln_b feed only the deleted adj_static -> unused.

    float* qws = (float*)d_ws;                           // 8*2048*128 f32 = 8 MB
    float* kws = qws + (size_t)BATCH * NODES * DTOT;     // 8*1024*128 f32 = 4 MB
    float* adj = (float*)d_out;

    proj_qk<<<dim3(BATCH * 96), dim3(256), 0, stream>>>(x, Wq, bq, Wk, bk, qws, kws);
    scores_gemm<<<dim3(BATCH * 512), dim3(256), 0, stream>>>(qws, kws, mlpw, mlpb, adj);
    topk_write<<<dim3(BATCH * 512), dim3(256), 0, stream>>>(adj);
}

// Round 3
// 197.631 us; speedup vs baseline: 2.4299x; 1.2116x over previous
//
#include <hip/hip_runtime.h>
#include <cstdint>
#include <cstddef>

#define BATCH 8
#define NODES 2048
#define IN_DIM 64
#define DTOT 128
#define NKEY 1024
#define LDK 136   // f16 row stride for k LDS tiles (padding: +8 f16 breaks 256B power-of-2 stride)

typedef _Float16 half8v __attribute__((ext_vector_type(8)));
typedef _Float16 half4v __attribute__((ext_vector_type(4)));
typedef float float4v __attribute__((ext_vector_type(4)));

__device__ __forceinline__ unsigned long long shfl_xor_u64(unsigned long long x, int mask) {
    int lo = (int)(unsigned)(x & 0xffffffffull);
    int hi = (int)(unsigned)(x >> 32);
    lo = __shfl_xor(lo, mask, 64);
    hi = __shfl_xor(hi, mask, 64);
    return ((unsigned long long)(unsigned)hi << 32) | (unsigned)lo;
}

__device__ __forceinline__ unsigned long long make_key(float v, int idx) {
    unsigned u = __float_as_uint(v);
    u = (u & 0x80000000u) ? ~u : (u | 0x80000000u);
    return ((unsigned long long)u << 32) | (unsigned)(1023 - idx);
}

// ---------------- Kernel 1: q/k projection (fp32, unchanged from R2) ----------------
__global__ __launch_bounds__(256) void proj_qk(
    const float* __restrict__ x, const float* __restrict__ Wq, const float* __restrict__ bq,
    const float* __restrict__ Wk, const float* __restrict__ bk,
    float* __restrict__ qws, float* __restrict__ kws)
{
    __shared__ float xs[64 * 68];
    __shared__ float wsh[64 * 68];

    const int t = threadIdx.x;
    const int blk = blockIdx.x;
    const int b = blk / 96;
    const int idx = blk - b * 96;

    const float* W; const float* bias; float* out;
    int nbase, cbase; size_t orow;
    if (idx < 64) {
        int nt = idx >> 1, ct = idx & 1;
        nbase = nt * 64; cbase = ct * 64;
        W = Wq; bias = bq; out = qws;
        orow = (size_t)(b * NODES + nbase);
    } else {
        int i2 = idx - 64;
        int nt = i2 >> 1, ct = i2 & 1;
        nbase = nt * 64; cbase = ct * 64;
        W = Wk; bias = bk; out = kws;
        orow = (size_t)(b * NKEY + nbase);
    }

    #pragma unroll
    for (int rep = 0; rep < 4; ++rep) {
        int f = rep * 256 + t;
        int r = f >> 4, d4 = f & 15;
        float4 xv = *(const float4*)(x + ((size_t)(b * NODES + nbase + r)) * IN_DIM + d4 * 4);
        *(float4*)(xs + r * 68 + d4 * 4) = xv;
        float4 wv = *(const float4*)(W + (size_t)(cbase + r) * IN_DIM + d4 * 4);
        *(float4*)(wsh + r * 68 + d4 * 4) = wv;
    }
    __syncthreads();

    const int w = t >> 6, l = t & 63;
    const int n_sel = w * 4 + (l >> 4);
    const int ul = l & 15;

    float acc[4][4];
    #pragma unroll
    for (int i = 0; i < 4; ++i)
        #pragma unroll
        for (int j = 0; j < 4; ++j) acc[i][j] = 0.f;

    #pragma unroll
    for (int d4 = 0; d4 < 16; ++d4) {
        float4 xv[4], wv[4];
        #pragma unroll
        for (int i = 0; i < 4; ++i)
            xv[i] = *(const float4*)(xs + (n_sel * 4 + i) * 68 + d4 * 4);
        #pragma unroll
        for (int j = 0; j < 4; ++j)
            wv[j] = *(const float4*)(wsh + (j * 16 + ul) * 68 + d4 * 4);
        #pragma unroll
        for (int i = 0; i < 4; ++i)
            #pragma unroll
            for (int j = 0; j < 4; ++j)
                acc[i][j] += xv[i].x * wv[j].x + xv[i].y * wv[j].y +
                             xv[i].z * wv[j].z + xv[i].w * wv[j].w;
    }

    #pragma unroll
    for (int j = 0; j < 4; ++j) {
        float bv = bias[cbase + j * 16 + ul];
        #pragma unroll
        for (int i = 0; i < 4; ++i)
            out[(orow + n_sel * 4 + i) * DTOT + cbase + j * 16 + ul] = acc[i][j] + bv;
    }
}

// ---------------- Kernel 2: MFMA split-fp16 scores -> stash in d_out cols 1024.. ----------------
// Block: 64 n-rows x 64 u-cols. Wave w: rows [w*16, w*16+16) x all 64 u.
// a_h = (q_h . k_h)/sqrt(32) via 4 MFMAs: qh*kh + qh*kl + ql*kh + ql*kl (split-fp16 exact to ~2^-22).
__global__ __launch_bounds__(256, 2) void scores_mfma(
    const float* __restrict__ qws, const float* __restrict__ kws,
    const float* __restrict__ mlpw, const float* __restrict__ mlpb,
    float* __restrict__ adj)
{
    __shared__ _Float16 khs[64 * LDK];
    __shared__ _Float16 kls[64 * LDK];

    const int t = threadIdx.x;
    const int blk = blockIdx.x;
    const int b = blk >> 9;
    const int rem = blk & 511;
    const int nb = (rem >> 4) * 64;
    const int ub = (rem & 15) * 64;

    const int w = t >> 6, l = t & 63;
    const int quad = l >> 4, lane16 = l & 15;

    // ---- load A fragments (q rows) straight from global, convert to hi/lo fp16 ----
    const int arow = b * NODES + nb + w * 16 + lane16;
    half8v Ah[4], Al[4];
    #pragma unroll
    for (int h = 0; h < 4; ++h) {
        const float* qp = qws + (size_t)arow * DTOT + h * 32 + quad * 8;
        float4 f0 = *(const float4*)(qp);
        float4 f1 = *(const float4*)(qp + 4);
        float tmp[8] = {f0.x, f0.y, f0.z, f0.w, f1.x, f1.y, f1.z, f1.w};
        #pragma unroll
        for (int e = 0; e < 8; ++e) {
            _Float16 hi = (_Float16)tmp[e];
            Ah[h][e] = hi;
            Al[h][e] = (_Float16)(tmp[e] - (float)hi);
        }
    }

    // ---- stage k tile (64 u-rows x 128) as hi/lo fp16 in LDS ----
    #pragma unroll
    for (int rep = 0; rep < 8; ++rep) {
        int f = rep * 256 + t;
        int r = f >> 5, c = f & 31;     // c: 16B chunk of fp32 (4 floats)
        float4 v = *(const float4*)(kws + ((size_t)(b * NKEY + ub + r)) * DTOT + c * 4);
        float tmp[4] = {v.x, v.y, v.z, v.w};
        half4v h4, l4;
        #pragma unroll
        for (int e = 0; e < 4; ++e) {
            _Float16 hi = (_Float16)tmp[e];
            h4[e] = hi;
            l4[e] = (_Float16)(tmp[e] - (float)hi);
        }
        *(half4v*)(&khs[r * LDK + c * 4]) = h4;
        *(half4v*)(&kls[r * LDK + c * 4]) = l4;
    }
    __syncthreads();

    float mw[4][4], mb4[4];
    #pragma unroll
    for (int o = 0; o < 4; ++o) {
        mb4[o] = mlpb[o];
        #pragma unroll
        for (int h = 0; h < 4; ++h) mw[o][h] = mlpw[o * 4 + h];
    }
    const float INV = 0.17677669529663687f;  // 1/sqrt(32)

    #pragma unroll
    for (int ut = 0; ut < 4; ++ut) {
        // B fragments for this 16-u tile
        half8v Bh[4], Bl[4];
        #pragma unroll
        for (int h = 0; h < 4; ++h) {
            Bh[h] = *(const half8v*)(&khs[(ut * 16 + lane16) * LDK + h * 32 + quad * 8]);
            Bl[h] = *(const half8v*)(&kls[(ut * 16 + lane16) * LDK + h * 32 + quad * 8]);
        }
        float4v C[4];
        #pragma unroll
        for (int h = 0; h < 4; ++h) {
            float4v c = {0.f, 0.f, 0.f, 0.f};
            c = __builtin_amdgcn_mfma_f32_16x16x32_f16(Ah[h], Bh[h], c, 0, 0, 0);
            c = __builtin_amdgcn_mfma_f32_16x16x32_f16(Ah[h], Bl[h], c, 0, 0, 0);
            c = __builtin_amdgcn_mfma_f32_16x16x32_f16(Al[h], Bh[h], c, 0, 0, 0);
            c = __builtin_amdgcn_mfma_f32_16x16x32_f16(Al[h], Bl[h], c, 0, 0, 0);
            C[h] = c;
        }
        // epilogue: lane holds rows quad*4+r (r=0..3), col = lane16
        #pragma unroll
        for (int r = 0; r < 4; ++r) {
            float a0 = C[0][r] * INV, a1 = C[1][r] * INV;
            float a2 = C[2][r] * INV, a3 = C[3][r] * INV;
            float ssum = a0 + a1 + a2 + a3;
            #pragma unroll
            for (int o = 0; o < 4; ++o) {
                float to = mw[o][0] * a0 + mw[o][1] * a1 + mw[o][2] * a2 + mw[o][3] * a3 + mb4[o];
                ssum += fmaxf(to, 0.f);
            }
            const size_t rowp = ((size_t)(b * NODES + nb + w * 16 + quad * 4 + r)) * NODES + NKEY;
            adj[rowp + ub + ut * 16 + lane16] = ssum;
        }
    }
}

// ---------------- Kernel 3: per-row top-32 + final adjacency write (unchanged) ----------------
__global__ __launch_bounds__(256) void topk_write(float* __restrict__ adj)
{
    __shared__ float scrow[4][1024];
    __shared__ unsigned long long cand[4][64];

    const int t = threadIdx.x;
    const int blk = blockIdx.x;
    const int b = blk >> 9;
    const int r0 = (blk & 511) * 4;
    const int w = t >> 6, l = t & 63;

    const int n = r0 + w;
    float* rowptr = adj + ((size_t)(b * NODES + n)) * NODES;
    const float* S = rowptr + NKEY;

    float v[16];
    #pragma unroll
    for (int jj = 0; jj < 16; ++jj) v[jj] = S[l + (jj << 6)];

    float lm = v[0];
    #pragma unroll
    for (int jj = 1; jj < 16; ++jj) lm = fmaxf(lm, v[jj]);

    float s = lm;
    #pragma unroll
    for (int k = 2; k <= 64; k <<= 1) {
        #pragma unroll
        for (int j = k >> 1; j > 0; j >>= 1) {
            float o = __shfl_xor(s, j, 64);
            bool up = ((l & k) == 0);
            bool lower = ((l & j) == 0);
            float mx = fmaxf(s, o), mn = fminf(s, o);
            s = (up == lower) ? mx : mn;
        }
    }
    const float T0 = __shfl(s, 31, 64);

    cand[w][l] = 0ull;
    __builtin_amdgcn_wave_barrier();
    int total = 0;
    #pragma unroll
    for (int jj = 0; jj < 16; ++jj) {
        bool p = (v[jj] >= T0);
        unsigned long long m = __ballot(p);
        if (p) {
            int pos = total + __popcll(m & ((1ull << l) - 1ull));
            if (pos < 64) cand[w][pos] = make_key(v[jj], l + (jj << 6));
        }
        total += (int)__popcll(m);
    }
    __builtin_amdgcn_wave_barrier();

    unsigned long long key;
    if (total <= 64) {
        key = cand[w][l];
        #pragma unroll
        for (int k = 2; k <= 64; k <<= 1) {
            #pragma unroll
            for (int j = k >> 1; j > 0; j >>= 1) {
                unsigned long long o = shfl_xor_u64(key, j);
                bool up = ((l & k) == 0);
                bool lower = ((l & j) == 0);
                unsigned long long mx = key > o ? key : o;
                unsigned long long mn = key > o ? o : key;
                key = (up == lower) ? mx : mn;
            }
        }
    } else {
        float selv = 0.f; int seli = 0;
        #pragma unroll 1
        for (int it = 0; it < 32; ++it) {
            float bv = -3.4e38f; int bi = 0x7fffffff;
            #pragma unroll
            for (int jj = 0; jj < 16; ++jj) {
                int idx = l + (jj << 6);
                if (v[jj] > bv) { bv = v[jj]; bi = idx; }
            }
            #pragma unroll
            for (int off = 1; off < 64; off <<= 1) {
                float ov = __shfl_xor(bv, off, 64);
                int oi = __shfl_xor(bi, off, 64);
                if (ov > bv || (ov == bv && oi < bi)) { bv = ov; bi = oi; }
            }
            if (l == it) { selv = bv; seli = bi; }
            if ((bi & 63) == l) {
                int slot = bi >> 6;
                #pragma unroll
                for (int jj = 0; jj < 16; ++jj) if (jj == slot) v[jj] = -3.4e38f;
            }
        }
        key = (l < 32) ? make_key(selv, seli) : 0ull;
    }

    __builtin_amdgcn_wave_barrier();
    #pragma unroll
    for (int jj = 0; jj < 16; ++jj) scrow[w][l + (jj << 6)] = 0.f;
    __builtin_amdgcn_wave_barrier();
    if (l < 32) {
        unsigned hi = (unsigned)(key >> 32);
        float val = __uint_as_float((hi & 0x80000000u) ? (hi & 0x7fffffffu) : ~hi);
        int idx = 1023 - (int)(key & 0xffffffffu);
        scrow[w][idx] = val;
    }
    __builtin_amdgcn_wave_barrier();

    #pragma unroll
    for (int jj = 0; jj < 8; ++jj) {
        int c4 = jj * 64 + l;
        float4 val;
        if (c4 < 256) val = *(const float4*)(&scrow[w][c4 * 4]);
        else          val = make_float4(0.f, 0.f, 0.f, 0.f);
        *(float4*)(rowptr + c4 * 4) = val;
    }
}

extern "C" void kernel_launch(void* const* d_in, const int* in_sizes, int n_in,
                              void* d_out, int out_size, void* d_ws, size_t ws_size,
                              hipStream_t stream) {
    const float* x    = (const float*)d_in[0];
    const float* Wq   = (const float*)d_in[1];
    const float* bq   = (const float*)d_in[2];
    const float* Wk   = (const float*)d_in[3];
    const float* bk   = (const float*)d_in[4];
    const float* mlpw = (const float*)d_in[5];
    const float* mlpb = (const float*)d_in[6];
    // ln_g, ln_b feed only the deleted adj_static -> unused.

    float* qws = (float*)d_ws;                           // 8*2048*128 f32 = 8 MB
    float* kws = qws + (size_t)BATCH * NODES * DTOT;     // 8*1024*128 f32 = 4 MB
    float* adj = (float*)d_out;

    proj_qk<<<dim3(BATCH * 96), dim3(256), 0, stream>>>(x, Wq, bq, Wk, bk, qws, kws);
    scores_mfma<<<dim3(BATCH * 512), dim3(256), 0, stream>>>(qws, kws, mlpw, mlpb, adj);
    topk_write<<<dim3(BATCH * 512), dim3(256), 0, stream>>>(adj);
}

// Round 4
// 191.115 us; speedup vs baseline: 2.5128x; 1.0341x over previous
//
#include <hip/hip_runtime.h>
#include <cstdint>
#include <cstddef>

#define BATCH 8
#define NODES 2048
#define IN_DIM 64
#define DTOT 128
#define NKEY 1024
#define LDK 136   // f16 row stride for k LDS tiles: 2-way bank aliasing only (free)

typedef _Float16 half8v __attribute__((ext_vector_type(8)));
typedef float float4v __attribute__((ext_vector_type(4)));

__device__ __forceinline__ unsigned long long make_key(float v, int idx) {
    unsigned u = __float_as_uint(v);
    u = (u & 0x80000000u) ? ~u : (u | 0x80000000u);
    return ((unsigned long long)u << 32) | (unsigned)(1023 - idx);
}

// ---------------- Kernel 1: q/k projection -> split-fp16 planes ----------------
// Per batch: 64 q-blocks (32 n-tiles x 2 c-tiles) + 32 k-blocks = 96 blocks.
__global__ __launch_bounds__(256) void proj_qk(
    const float* __restrict__ x, const float* __restrict__ Wq, const float* __restrict__ bq,
    const float* __restrict__ Wk, const float* __restrict__ bk,
    _Float16* __restrict__ qh, _Float16* __restrict__ ql,
    _Float16* __restrict__ kh, _Float16* __restrict__ kl)
{
    __shared__ float xs[64 * 68];
    __shared__ float wsh[64 * 68];

    const int t = threadIdx.x;
    const int blk = blockIdx.x;
    const int b = blk / 96;
    const int idx = blk - b * 96;

    const float* W; const float* bias;
    _Float16* oh; _Float16* ol;
    int nbase, cbase; size_t orow;
    if (idx < 64) {
        int nt = idx >> 1, ct = idx & 1;
        nbase = nt * 64; cbase = ct * 64;
        W = Wq; bias = bq; oh = qh; ol = ql;
        orow = (size_t)(b * NODES + nbase);
    } else {
        int i2 = idx - 64;
        int nt = i2 >> 1, ct = i2 & 1;
        nbase = nt * 64; cbase = ct * 64;
        W = Wk; bias = bk; oh = kh; ol = kl;
        orow = (size_t)(b * NKEY + nbase);
    }

    #pragma unroll
    for (int rep = 0; rep < 4; ++rep) {
        int f = rep * 256 + t;
        int r = f >> 4, d4 = f & 15;
        float4 xv = *(const float4*)(x + ((size_t)(b * NODES + nbase + r)) * IN_DIM + d4 * 4);
        *(float4*)(xs + r * 68 + d4 * 4) = xv;
        float4 wv = *(const float4*)(W + (size_t)(cbase + r) * IN_DIM + d4 * 4);
        *(float4*)(wsh + r * 68 + d4 * 4) = wv;
    }
    __syncthreads();

    const int w = t >> 6, l = t & 63;
    const int n_sel = w * 4 + (l >> 4);
    const int ul = l & 15;

    float acc[4][4];
    #pragma unroll
    for (int i = 0; i < 4; ++i)
        #pragma unroll
        for (int j = 0; j < 4; ++j) acc[i][j] = 0.f;

    #pragma unroll
    for (int d4 = 0; d4 < 16; ++d4) {
        float4 xv[4], wv[4];
        #pragma unroll
        for (int i = 0; i < 4; ++i)
            xv[i] = *(const float4*)(xs + (n_sel * 4 + i) * 68 + d4 * 4);
        #pragma unroll
        for (int j = 0; j < 4; ++j)
            wv[j] = *(const float4*)(wsh + (j * 16 + ul) * 68 + d4 * 4);
        #pragma unroll
        for (int i = 0; i < 4; ++i)
            #pragma unroll
            for (int j = 0; j < 4; ++j)
                acc[i][j] += xv[i].x * wv[j].x + xv[i].y * wv[j].y +
                             xv[i].z * wv[j].z + xv[i].w * wv[j].w;
    }

    #pragma unroll
    for (int j = 0; j < 4; ++j) {
        float bv = bias[cbase + j * 16 + ul];
        #pragma unroll
        for (int i = 0; i < 4; ++i) {
            float a = acc[i][j] + bv;
            _Float16 hi = (_Float16)a;
            size_t p = (orow + n_sel * 4 + i) * DTOT + cbase + j * 16 + ul;
            oh[p] = hi;
            ol[p] = (_Float16)(a - (float)hi);
        }
    }
}

// ---------------- Kernel 2: MFMA scores (pre-split fp16) -> stash in d_out cols 1024.. ----------------
__global__ __launch_bounds__(256, 4) void scores_mfma(
    const _Float16* __restrict__ qh, const _Float16* __restrict__ ql,
    const _Float16* __restrict__ kh, const _Float16* __restrict__ kl,
    const float* __restrict__ mlpw, const float* __restrict__ mlpb,
    float* __restrict__ adj)
{
    __shared__ _Float16 khs[64 * LDK];
    __shared__ _Float16 kls[64 * LDK];

    const int t = threadIdx.x;
    const int blk = blockIdx.x;
    const int b = blk >> 9;
    const int rem = blk & 511;
    const int nb = (rem >> 4) * 64;
    const int ub = (rem & 15) * 64;

    const int w = t >> 6, l = t & 63;
    const int quad = l >> 4, lane16 = l & 15;

    // A fragments: straight 16B fp16 loads (A[m=lane&15][k=quad*8+j])
    const size_t arow = (size_t)(b * NODES + nb + w * 16 + lane16);
    half8v Ah[4], Al[4];
    #pragma unroll
    for (int h = 0; h < 4; ++h) {
        Ah[h] = *(const half8v*)(qh + arow * DTOT + h * 32 + quad * 8);
        Al[h] = *(const half8v*)(ql + arow * DTOT + h * 32 + quad * 8);
    }

    // stage k tile: 64 u-rows x 128 f16, hi+lo planes (16B chunks, zero conversion)
    #pragma unroll
    for (int rep = 0; rep < 4; ++rep) {
        int f = rep * 256 + t;
        int r = f >> 4, c = f & 15;
        size_t src = ((size_t)(b * NKEY + ub + r)) * DTOT + c * 8;
        *(half8v*)(&khs[r * LDK + c * 8]) = *(const half8v*)(kh + src);
        *(half8v*)(&kls[r * LDK + c * 8]) = *(const half8v*)(kl + src);
    }
    __syncthreads();

    float mw[4][4], mb4[4];
    #pragma unroll
    for (int o = 0; o < 4; ++o) {
        mb4[o] = mlpb[o];
        #pragma unroll
        for (int h = 0; h < 4; ++h) mw[o][h] = mlpw[o * 4 + h];
    }
    const float INV = 0.17677669529663687f;  // 1/sqrt(32)

    #pragma unroll
    for (int ut = 0; ut < 4; ++ut) {
        half8v Bh[4], Bl[4];
        #pragma unroll
        for (int h = 0; h < 4; ++h) {
            Bh[h] = *(const half8v*)(&khs[(ut * 16 + lane16) * LDK + h * 32 + quad * 8]);
            Bl[h] = *(const half8v*)(&kls[(ut * 16 + lane16) * LDK + h * 32 + quad * 8]);
        }
        float4v C[4];
        #pragma unroll
        for (int h = 0; h < 4; ++h) {
            float4v c = {0.f, 0.f, 0.f, 0.f};
            c = __builtin_amdgcn_mfma_f32_16x16x32_f16(Ah[h], Bh[h], c, 0, 0, 0);
            c = __builtin_amdgcn_mfma_f32_16x16x32_f16(Ah[h], Bl[h], c, 0, 0, 0);
            c = __builtin_amdgcn_mfma_f32_16x16x32_f16(Al[h], Bh[h], c, 0, 0, 0);
            C[h] = c;
        }
        #pragma unroll
        for (int r = 0; r < 4; ++r) {
            float a0 = C[0][r] * INV, a1 = C[1][r] * INV;
            float a2 = C[2][r] * INV, a3 = C[3][r] * INV;
            float ssum = a0 + a1 + a2 + a3;
            #pragma unroll
            for (int o = 0; o < 4; ++o) {
                float to = mw[o][0] * a0 + mw[o][1] * a1 + mw[o][2] * a2 + mw[o][3] * a3 + mb4[o];
                ssum += fmaxf(to, 0.f);
            }
            const size_t rowp = ((size_t)(b * NODES + nb + w * 16 + quad * 4 + r)) * NODES + NKEY;
            adj[rowp + ub + ut * 16 + lane16] = ssum;
        }
    }
}

// ---------------- Kernel 3: per-row top-32 via rank selection + final write ----------------
__global__ __launch_bounds__(256) void topk_write(float* __restrict__ adj)
{
    __shared__ float scrow[4][1024];
    __shared__ unsigned long long cand[4][64];
    __shared__ float maxb[4][64];

    const int t = threadIdx.x;
    const int blk = blockIdx.x;
    const int b = blk >> 9;
    const int r0 = (blk & 511) * 4;
    const int w = t >> 6, l = t & 63;

    const int n = r0 + w;
    float* rowptr = adj + ((size_t)(b * NODES + n)) * NODES;
    const float4* S4 = (const float4*)(rowptr + NKEY);

    // lane l holds indices jj*256 + l*4 + e
    float4 vv[4];
    #pragma unroll
    for (int jj = 0; jj < 4; ++jj) vv[jj] = S4[jj * 64 + l];

    float m = vv[0].x;
    #pragma unroll
    for (int jj = 0; jj < 4; ++jj) {
        m = fmaxf(m, vv[jj].x); m = fmaxf(m, vv[jj].y);
        m = fmaxf(m, vv[jj].z); m = fmaxf(m, vv[jj].w);
    }

    // threshold T = 32nd-largest lane-max via pipelined LDS-broadcast rank count
    maxb[w][l] = m;
    __builtin_amdgcn_wave_barrier();
    int r = 0;
    #pragma unroll
    for (int j = 0; j < 64; ++j) r += (maxb[w][j] > m) ? 1 : 0;
    float sel = (r <= 31) ? m : 3.4e38f;
    #pragma unroll
    for (int off = 1; off < 64; off <<= 1)
        sel = fminf(sel, __shfl_xor(sel, off, 64));
    const float T = sel;   // >= 32 row elements are >= T, and T <= true 32nd value

    // ballot-compact candidates >= T
    cand[w][l] = 0ull;
    __builtin_amdgcn_wave_barrier();
    int total = 0;
    #pragma unroll
    for (int jj = 0; jj < 4; ++jj) {
        #pragma unroll
        for (int e = 0; e < 4; ++e) {
            float v = (e == 0) ? vv[jj].x : (e == 1) ? vv[jj].y : (e == 2) ? vv[jj].z : vv[jj].w;
            bool p = (v >= T);
            unsigned long long msk = __ballot(p);
            if (p) {
                int pos = total + __popcll(msk & ((1ull << l) - 1ull));
                if (pos < 64) cand[w][pos] = make_key(v, jj * 256 + l * 4 + e);
            }
            total += (int)__popcll(msk);
        }
    }
    __builtin_amdgcn_wave_barrier();

    bool win = false; float wval = 0.f; int widx = 0;
    if (total <= 64) {
        unsigned long long key = cand[w][l];
        int r2 = 0;
        #pragma unroll
        for (int j = 0; j < 64; ++j) r2 += (cand[w][j] > key) ? 1 : 0;
        if (key != 0ull && r2 < 32) {
            win = true;
            unsigned hi = (unsigned)(key >> 32);
            wval = __uint_as_float((hi & 0x80000000u) ? (hi & 0x7fffffffu) : ~hi);
            widx = 1023 - (int)(key & 0xffffffffu);
        }
    } else {
        // rare fallback: exact 32-round butterfly extraction
        float vals[16];
        #pragma unroll
        for (int jj = 0; jj < 4; ++jj) {
            vals[jj * 4 + 0] = vv[jj].x; vals[jj * 4 + 1] = vv[jj].y;
            vals[jj * 4 + 2] = vv[jj].z; vals[jj * 4 + 3] = vv[jj].w;
        }
        float selv = 0.f; int seli = 0;
        #pragma unroll 1
        for (int it = 0; it < 32; ++it) {
            float bv = -3.4e38f; int bi = 0x7fffffff;
            #pragma unroll
            for (int s = 0; s < 16; ++s) {
                int idx = (s >> 2) * 256 + l * 4 + (s & 3);
                if (vals[s] > bv) { bv = vals[s]; bi = idx; }
            }
            #pragma unroll
            for (int off = 1; off < 64; off <<= 1) {
                float ov = __shfl_xor(bv, off, 64);
                int oi = __shfl_xor(bi, off, 64);
                if (ov > bv || (ov == bv && oi < bi)) { bv = ov; bi = oi; }
            }
            if (l == it) { selv = bv; seli = bi; }
            if (((bi >> 2) & 63) == l) {
                int slot = ((bi >> 8) << 2) + (bi & 3);
                #pragma unroll
                for (int s = 0; s < 16; ++s) if (s == slot) vals[s] = -3.4e38f;
            }
        }
        if (l < 32) { win = true; wval = selv; widx = seli; }
    }

    // rebuild lower half of the row in LDS (in-order DS pipe per wave)
    __builtin_amdgcn_wave_barrier();
    #pragma unroll
    for (int jj = 0; jj < 16; ++jj) scrow[w][l + (jj << 6)] = 0.f;
    __builtin_amdgcn_wave_barrier();
    if (win) scrow[w][widx] = wval;
    __builtin_amdgcn_wave_barrier();

    // stream out the full 2048-wide row (upper half zeros, overwriting the stash)
    #pragma unroll
    for (int jj = 0; jj < 8; ++jj) {
        int c4 = jj * 64 + l;
        float4 val;
        if (c4 < 256) val = *(const float4*)(&scrow[w][c4 * 4]);
        else          val = make_float4(0.f, 0.f, 0.f, 0.f);
        *(float4*)(rowptr + c4 * 4) = val;
    }
}

extern "C" void kernel_launch(void* const* d_in, const int* in_sizes, int n_in,
                              void* d_out, int out_size, void* d_ws, size_t ws_size,
                              hipStream_t stream) {
    const float* x    = (const float*)d_in[0];
    const float* Wq   = (const float*)d_in[1];
    const float* bq   = (const float*)d_in[2];
    const float* Wk   = (const float*)d_in[3];
    const float* bk   = (const float*)d_in[4];
    const float* mlpw = (const float*)d_in[5];
    const float* mlpb = (const float*)d_in[6];
    // ln_g, ln_b feed only the deleted adj_static -> unused.

    _Float16* qh = (_Float16*)d_ws;                       // 8*2048*128 f16 = 4 MB
    _Float16* ql = qh + (size_t)BATCH * NODES * DTOT;     // 4 MB
    _Float16* kh = ql + (size_t)BATCH * NODES * DTOT;     // 8*1024*128 f16 = 2 MB
    _Float16* kl = kh + (size_t)BATCH * NKEY * DTOT;      // 2 MB   (total 12 MB)
    float* adj = (float*)d_out;

    proj_qk<<<dim3(BATCH * 96), dim3(256), 0, stream>>>(x, Wq, bq, Wk, bk, qh, ql, kh, kl);
    scores_mfma<<<dim3(BATCH * 512), dim3(256), 0, stream>>>(qh, ql, kh, kl, mlpw, mlpb, adj);
    topk_write<<<dim3(BATCH * 512), dim3(256), 0, stream>>>(adj);
}